// Round 3
// baseline (524.088 us; speedup 1.0000x reference)
//
#include <hip/hip_runtime.h>

typedef unsigned short u16;
typedef unsigned int   u32;
typedef unsigned long long u64;

typedef __bf16 bf16_t;
typedef bf16_t bf16x8 __attribute__((ext_vector_type(8)));
typedef float  f32x4  __attribute__((ext_vector_type(4)));

static constexpr int Bz = 4, Sq = 1024, Dm = 1024, Hn = 16, Ff = 4096, Mtok = 4096;

static __device__ __forceinline__ u16 f2bf(float f) {
  u32 u = __builtin_bit_cast(u32, f);
  u32 r = u + 0x7fff + ((u >> 16) & 1);
  return (u16)(r >> 16);
}

static __device__ __forceinline__ void gld16(const u16* g, u16* l) {
  __builtin_amdgcn_global_load_lds((const __attribute__((address_space(1))) u32*)g,
                                   (__attribute__((address_space(3))) u32*)l, 16, 0, 0);
}

// ---------------- fp32 -> bf16 cast ----------------
__global__ void k_cvt(const float* __restrict__ src, u16* __restrict__ dst, int n4) {
  int i = blockIdx.x * 256 + threadIdx.x;
  if (i >= n4) return;
  float4 v = reinterpret_cast<const float4*>(src)[i];
  ushort4 o;
  o.x = f2bf(v.x); o.y = f2bf(v.y); o.z = f2bf(v.z); o.w = f2bf(v.w);
  reinterpret_cast<ushort4*>(dst)[i] = o;
}

// ---------------- mask -> bitmask + row_valid ----------------
__global__ void k_maskpack(const int* __restrict__ mask, u32* __restrict__ mb,
                           u32* __restrict__ rv) {
  int row = blockIdx.x;
  int t = threadIdx.x, w = t >> 6, lane = t & 63;
  const int* mrow = mask + (size_t)row * Sq;
  __shared__ u32 red[4];
  u32 any = 0;
#pragma unroll
  for (int i = 0; i < 4; i++) {
    int chunk = w * 4 + i;
    int k = chunk * 64 + lane;
    u64 bal = __ballot(mrow[k] != 0);
    any |= (u32)(bal | (bal >> 32));
    if (lane == 0) mb[(size_t)row * 32 + chunk * 2]     = (u32)bal;
    if (lane == 1) mb[(size_t)row * 32 + chunk * 2 + 1] = (u32)(bal >> 32);
  }
  if (lane == 0) red[w] = any;
  __syncthreads();
  if (t == 0) rv[row] = (red[0] | red[1] | red[2] | red[3]) ? 1u : 0u;
}

// ---------------- LayerNorm (one block per row) -> bf16 ----------------
__global__ void k_ln(const float* __restrict__ x, const float* __restrict__ g,
                     const float* __restrict__ bb, u16* __restrict__ out) {
  int row = blockIdx.x, t = threadIdx.x;
  float4 v = reinterpret_cast<const float4*>(x + (size_t)row * Dm)[t];
  float s  = v.x + v.y + v.z + v.w;
  float s2 = v.x * v.x + v.y * v.y + v.z * v.z + v.w * v.w;
#pragma unroll
  for (int m = 1; m < 64; m <<= 1) { s += __shfl_xor(s, m); s2 += __shfl_xor(s2, m); }
  __shared__ float rs[4], rs2[4];
  int w = t >> 6;
  if ((t & 63) == 0) { rs[w] = s; rs2[w] = s2; }
  __syncthreads();
  s  = rs[0] + rs[1] + rs[2] + rs[3];
  s2 = rs2[0] + rs2[1] + rs2[2] + rs2[3];
  float mu  = s * (1.0f / Dm);
  float var = s2 * (1.0f / Dm) - mu * mu;
  float r = rsqrtf(var + 1e-5f);
  float4 gv = reinterpret_cast<const float4*>(g)[t];
  float4 bv = reinterpret_cast<const float4*>(bb)[t];
  ushort4 o;
  o.x = f2bf((v.x - mu) * r * gv.x + bv.x);
  o.y = f2bf((v.y - mu) * r * gv.y + bv.y);
  o.z = f2bf((v.z - mu) * r * gv.z + bv.z);
  o.w = f2bf((v.w - mu) * r * gv.w + bv.w);
  reinterpret_cast<ushort4*>(out + (size_t)row * Dm)[t] = o;
}

// ---------------- GEMM: C[M,N] = A[M,K] * Bw[N,K]^T (bf16 in, fp32 acc) ----------------
// MODE 0: store bf16
// MODE 1: f32 out = resid + acc
// MODE 2: bf16 out = gelu(acc + bias)
// MODE 3: f32 out = resid + (rv[row] ? acc + bias : 0)
template <int MODE>
__global__ __launch_bounds__(256)
void k_gemm(const u16* __restrict__ A, const u16* __restrict__ Bw,
            int M, int N, int K,
            const float* __restrict__ resid, const float* __restrict__ bias,
            const u32* __restrict__ rv, void* __restrict__ Cout) {
  __shared__ u16 As[128 * 64];
  __shared__ u16 Bs[128 * 64];
  const int t = threadIdx.x;
  const int lane = t & 63, w = t >> 6;
  const int wr = w >> 1, wc = w & 1;
  const int m0 = blockIdx.y * 128, n0 = blockIdx.x * 128;
  const int lr = lane & 15, lk = (lane >> 4) * 8;

  f32x4 acc[4][4] = {};

  for (int kt = 0; kt < K; kt += 64) {
#pragma unroll
    for (int i = 0; i < 4; i++) {
      int cc = i * 256 + t; int row = cc >> 3, c8 = cc & 7;
      gld16(A + (size_t)(m0 + row) * K + kt + c8 * 8, &As[cc * 8]);
    }
#pragma unroll
    for (int i = 0; i < 4; i++) {
      int cc = i * 256 + t; int row = cc >> 3, c8 = cc & 7;
      gld16(Bw + (size_t)(n0 + row) * K + kt + c8 * 8, &Bs[cc * 8]);
    }
    __syncthreads();
#pragma unroll
    for (int kk = 0; kk < 2; kk++) {
      bf16x8 af[4], bfg[4];
#pragma unroll
      for (int m = 0; m < 4; m++)
        af[m] = *reinterpret_cast<const bf16x8*>(&As[(wr * 64 + m * 16 + lr) * 64 + kk * 32 + lk]);
#pragma unroll
      for (int n = 0; n < 4; n++)
        bfg[n] = *reinterpret_cast<const bf16x8*>(&Bs[(wc * 64 + n * 16 + lr) * 64 + kk * 32 + lk]);
#pragma unroll
      for (int m = 0; m < 4; m++)
#pragma unroll
        for (int n = 0; n < 4; n++)
          acc[m][n] = __builtin_amdgcn_mfma_f32_16x16x32_bf16(af[m], bfg[n], acc[m][n], 0, 0, 0);
    }
    __syncthreads();
  }

#pragma unroll
  for (int m = 0; m < 4; m++) {
    const int rowb = m0 + wr * 64 + m * 16 + (lane >> 4) * 4;
#pragma unroll
    for (int n = 0; n < 4; n++) {
      const int col = n0 + wc * 64 + n * 16 + lr;
#pragma unroll
      for (int r = 0; r < 4; r++) {
        const int row = rowb + r;
        float v = acc[m][n][r];
        size_t idx = (size_t)row * N + col;
        if constexpr (MODE == 0) {
          ((u16*)Cout)[idx] = f2bf(v);
        } else if constexpr (MODE == 1) {
          ((float*)Cout)[idx] = resid[idx] + v;
        } else if constexpr (MODE == 2) {
          float xx = v + bias[col];
          float gl = 0.5f * xx * (1.0f + erff(xx * 0.70710678118f));
          ((u16*)Cout)[idx] = f2bf(gl);
        } else {
          float y = rv[row] ? (v + bias[col]) : 0.0f;
          ((float*)Cout)[idx] = resid[idx] + y;
        }
      }
    }
  }
}

// ---------------- Flash attention ----------------
// grid (S/64, B*H); 256 thr = 4 waves, each wave owns 16 q rows.
__global__ __launch_bounds__(256)
void k_attn(const u16* __restrict__ Qb, const u16* __restrict__ Kb,
            const u16* __restrict__ Vb, const u32* __restrict__ mb,
            u16* __restrict__ ctxb) {
  __shared__ u16 Qs[64 * 64];
  __shared__ u16 Ks[64 * 64];
  __shared__ u16 Vts[64 * 64];
  __shared__ u16 Ps[4 * 16 * 64];
  const int t = threadIdx.x, lane = t & 63, w = t >> 6;
  const int q0 = blockIdx.x * 64;
  const int bh = blockIdx.y, b = bh >> 4, h = bh & 15;
  const int lr = lane & 15, lkq = (lane >> 4) * 8;
  const size_t basebh = (size_t)b * Sq * Dm + h * 64;

  // stage Q (swizzled: elem col ^= (row&7)<<3, preserves 8-elem chunks)
  {
    int r = t >> 2, c0 = (t & 3) * 16;
    const u16* gp = Qb + basebh + (size_t)(q0 + r) * Dm + c0;
    uint4 v0 = *reinterpret_cast<const uint4*>(gp);
    uint4 v1 = *reinterpret_cast<const uint4*>(gp + 8);
    int sw = (r & 7) << 3;
    *reinterpret_cast<uint4*>(&Qs[r * 64 + (c0 ^ sw)]) = v0;
    *reinterpret_cast<uint4*>(&Qs[r * 64 + ((c0 + 8) ^ sw)]) = v1;
  }
  __syncthreads();

  bf16x8 qf[2];
  const int qrow = w * 16 + lr;
#pragma unroll
  for (int kk = 0; kk < 2; kk++)
    qf[kk] = *reinterpret_cast<const bf16x8*>(&Qs[qrow * 64 + ((kk * 32 + lkq) ^ ((qrow & 7) << 3))]);

  float m_i[4] = {-1e30f, -1e30f, -1e30f, -1e30f};
  float l_i[4] = {0.f, 0.f, 0.f, 0.f};
  f32x4 accO[4] = {};
  const int rq0 = (lane >> 4) * 4;

  for (int kt = 0; kt < Sq / 64; kt++) {
    __syncthreads();
    {
      int r = t >> 2, c0 = (t & 3) * 16;
      const u16* gp = Kb + basebh + (size_t)(kt * 64 + r) * Dm + c0;
      uint4 v0 = *reinterpret_cast<const uint4*>(gp);
      uint4 v1 = *reinterpret_cast<const uint4*>(gp + 8);
      int sw = (r & 7) << 3;
      *reinterpret_cast<uint4*>(&Ks[r * 64 + (c0 ^ sw)]) = v0;
      *reinterpret_cast<uint4*>(&Ks[r * 64 + ((c0 + 8) ^ sw)]) = v1;
      // V transposed into LDS: Vts[d][k]
      const u16* gv = Vb + basebh + (size_t)(kt * 64 + r) * Dm + c0;
      u16 tmp[16];
      *reinterpret_cast<uint4*>(&tmp[0]) = *reinterpret_cast<const uint4*>(gv);
      *reinterpret_cast<uint4*>(&tmp[8]) = *reinterpret_cast<const uint4*>(gv + 8);
#pragma unroll
      for (int j = 0; j < 16; j++) {
        int d = c0 + j;
        Vts[d * 64 + (r ^ ((d & 7) << 3))] = tmp[j];
      }
    }
    __syncthreads();

    // QK^T
    f32x4 sc[4];
#pragma unroll
    for (int n = 0; n < 4; n++) sc[n] = (f32x4){0.f, 0.f, 0.f, 0.f};
#pragma unroll
    for (int kk = 0; kk < 2; kk++) {
#pragma unroll
      for (int n = 0; n < 4; n++) {
        int krow = n * 16 + lr;
        bf16x8 kf = *reinterpret_cast<const bf16x8*>(
            &Ks[krow * 64 + ((kk * 32 + lkq) ^ ((krow & 7) << 3))]);
        sc[n] = __builtin_amdgcn_mfma_f32_16x16x32_bf16(qf[kk], kf, sc[n], 0, 0, 0);
      }
    }
    // mask words for this lane's 4 rows
    u32 mw[4][2];
#pragma unroll
    for (int r = 0; r < 4; r++) {
      int q = q0 + w * 16 + rq0 + r;
      mw[r][0] = mb[(size_t)(b * Sq + q) * 32 + kt * 2];
      mw[r][1] = mb[(size_t)(b * Sq + q) * 32 + kt * 2 + 1];
    }
    float rmax[4] = {-1e30f, -1e30f, -1e30f, -1e30f};
#pragma unroll
    for (int n = 0; n < 4; n++) {
      int kin = n * 16 + lr;
#pragma unroll
      for (int r = 0; r < 4; r++) {
        float sval = sc[n][r] * 0.125f;
        if (!((mw[r][kin >> 5] >> (kin & 31)) & 1)) sval = -1e9f;
        sc[n][r] = sval;
        rmax[r] = fmaxf(rmax[r], sval);
      }
    }
#pragma unroll
    for (int r = 0; r < 4; r++) {
#pragma unroll
      for (int mm = 1; mm < 16; mm <<= 1) rmax[r] = fmaxf(rmax[r], __shfl_xor(rmax[r], mm));
      float mnew = fmaxf(m_i[r], rmax[r]);
      float scale = __expf(m_i[r] - mnew);
      m_i[r] = mnew;
      l_i[r] *= scale;
#pragma unroll
      for (int n = 0; n < 4; n++) accO[n][r] *= scale;
    }
    float rsum[4] = {0.f, 0.f, 0.f, 0.f};
#pragma unroll
    for (int n = 0; n < 4; n++)
#pragma unroll
      for (int r = 0; r < 4; r++) {
        float p = __expf(sc[n][r] - m_i[r]);
        sc[n][r] = p;
        rsum[r] += p;
      }
#pragma unroll
    for (int r = 0; r < 4; r++) {
#pragma unroll
      for (int mm = 1; mm < 16; mm <<= 1) rsum[r] += __shfl_xor(rsum[r], mm);
      l_i[r] += rsum[r];
    }
    // P -> LDS (per-wave region, swizzled)
#pragma unroll
    for (int n = 0; n < 4; n++)
#pragma unroll
      for (int r = 0; r < 4; r++) {
        int row = rq0 + r;
        Ps[w * 1024 + row * 64 + ((n * 16 + lr) ^ ((row & 7) << 3))] = f2bf(sc[n][r]);
      }
    asm volatile("s_waitcnt lgkmcnt(0)" ::: "memory");
    __builtin_amdgcn_sched_barrier(0);
    // PV
    bf16x8 pf[2];
#pragma unroll
    for (int kk = 0; kk < 2; kk++)
      pf[kk] = *reinterpret_cast<const bf16x8*>(
          &Ps[w * 1024 + lr * 64 + ((kk * 32 + lkq) ^ ((lr & 7) << 3))]);
#pragma unroll
    for (int kk = 0; kk < 2; kk++) {
#pragma unroll
      for (int n = 0; n < 4; n++) {
        int d = n * 16 + lr;
        bf16x8 vf = *reinterpret_cast<const bf16x8*>(
            &Vts[d * 64 + ((kk * 32 + lkq) ^ ((d & 7) << 3))]);
        accO[n] = __builtin_amdgcn_mfma_f32_16x16x32_bf16(pf[kk], vf, accO[n], 0, 0, 0);
      }
    }
  }

#pragma unroll
  for (int r = 0; r < 4; r++) {
    float recip = (m_i[r] <= -0.9e9f || l_i[r] == 0.f) ? 0.f : 1.f / l_i[r];
    int grow = q0 + w * 16 + rq0 + r;
#pragma unroll
    for (int n = 0; n < 4; n++)
      ctxb[basebh + (size_t)grow * Dm + n * 16 + lr] = f2bf(accO[n][r] * recip);
  }
}

// ---------------- launch ----------------
extern "C" void kernel_launch(void* const* d_in, const int* in_sizes, int n_in,
                              void* d_out, int out_size, void* d_ws, size_t ws_size,
                              hipStream_t stream) {
  const float* x     = (const float*)d_in[0];
  const float* Wq    = (const float*)d_in[1];
  const float* Wk    = (const float*)d_in[2];
  const float* Wv    = (const float*)d_in[3];
  const float* Wo    = (const float*)d_in[4];
  const float* w1    = (const float*)d_in[5];
  const float* b1    = (const float*)d_in[6];
  const float* w2    = (const float*)d_in[7];
  const float* b2    = (const float*)d_in[8];
  const float* ln1g  = (const float*)d_in[9];
  const float* ln1b  = (const float*)d_in[10];
  const float* ln2g  = (const float*)d_in[11];
  const float* ln2b  = (const float*)d_in[12];
  const int*   mask  = (const int*)d_in[13];
  float* out = (float*)d_out;

  char* ws = (char*)d_ws;
  const size_t MB = 1024 * 1024;
  u16* wq_b = (u16*)(ws + 0 * MB);
  u16* wk_b = (u16*)(ws + 2 * MB);
  u16* wv_b = (u16*)(ws + 4 * MB);
  u16* wo_b = (u16*)(ws + 6 * MB);
  u16* w1_b = (u16*)(ws + 8 * MB);
  u16* w2_b = (u16*)(ws + 16 * MB);
  u16* h_b  = (u16*)(ws + 24 * MB);   // LN1 out; reused as LN2 out
  u16* qb   = (u16*)(ws + 32 * MB);
  u16* kb   = (u16*)(ws + 40 * MB);
  u16* vb   = (u16*)(ws + 48 * MB);
  u16* ctxb = (u16*)(ws + 56 * MB);
  float* x1 = (float*)(ws + 64 * MB);
  u32* mbits = (u32*)(ws + 80 * MB);
  u32* rv    = (u32*)(ws + 81 * MB);
  u16* a1b  = (u16*)(ws + 32 * MB);   // reuse q/k/v/ctx region (32MB)

  k_cvt<<<1024, 256, 0, stream>>>(Wq, wq_b, 262144);
  k_cvt<<<1024, 256, 0, stream>>>(Wk, wk_b, 262144);
  k_cvt<<<1024, 256, 0, stream>>>(Wv, wv_b, 262144);
  k_cvt<<<1024, 256, 0, stream>>>(Wo, wo_b, 262144);
  k_cvt<<<4096, 256, 0, stream>>>(w1, w1_b, 1048576);
  k_cvt<<<4096, 256, 0, stream>>>(w2, w2_b, 1048576);
  k_maskpack<<<4096, 256, 0, stream>>>(mask, mbits, rv);
  k_ln<<<4096, 256, 0, stream>>>(x, ln1g, ln1b, h_b);

  dim3 g1(Dm / 128, Mtok / 128);           // 8 x 32
  k_gemm<0><<<g1, 256, 0, stream>>>(h_b, wq_b, Mtok, Dm, Dm, nullptr, nullptr, nullptr, qb);
  k_gemm<0><<<g1, 256, 0, stream>>>(h_b, wk_b, Mtok, Dm, Dm, nullptr, nullptr, nullptr, kb);
  k_gemm<0><<<g1, 256, 0, stream>>>(h_b, wv_b, Mtok, Dm, Dm, nullptr, nullptr, nullptr, vb);

  dim3 ga(Sq / 64, Bz * Hn);               // 16 x 64
  k_attn<<<ga, 256, 0, stream>>>(qb, kb, vb, mbits, ctxb);

  k_gemm<1><<<g1, 256, 0, stream>>>(ctxb, wo_b, Mtok, Dm, Dm, x, nullptr, nullptr, x1);
  k_ln<<<4096, 256, 0, stream>>>(x1, ln2g, ln2b, h_b);

  dim3 g2(Ff / 128, Mtok / 128);           // 32 x 32
  k_gemm<2><<<g2, 256, 0, stream>>>(h_b, w1_b, Mtok, Ff, Dm, nullptr, b1, nullptr, a1b);

  dim3 g3(Dm / 128, Mtok / 128);           // 8 x 32
  k_gemm<3><<<g3, 256, 0, stream>>>(a1b, w2_b, Mtok, Dm, Ff, x1, b2, rv, out);
}

// Round 5
// 456.412 us; speedup vs baseline: 1.1483x; 1.1483x over previous
//
#include <hip/hip_runtime.h>

typedef unsigned short u16;
typedef unsigned int   u32;
typedef unsigned long long u64;

typedef __bf16 bf16_t;
typedef bf16_t bf16x8 __attribute__((ext_vector_type(8)));
typedef float  f32x4  __attribute__((ext_vector_type(4)));

static constexpr int Bz = 4, Sq = 1024, Dm = 1024, Hn = 16, Ff = 4096, Mtok = 4096;
static constexpr int QS = 3072;   // fused qkv row stride

static __device__ __forceinline__ u16 f2bf(float f) {
  u32 u = __builtin_bit_cast(u32, f);
  u32 r = u + 0x7fff + ((u >> 16) & 1);
  return (u16)(r >> 16);
}

static __device__ __forceinline__ void gld16(const u16* g, u16* l) {
  __builtin_amdgcn_global_load_lds((const __attribute__((address_space(1))) u32*)g,
                                   (__attribute__((address_space(3))) u32*)l, 16, 0, 0);
}

// ---------------- fp32 -> bf16 cast ----------------
__global__ void k_cvt(const float* __restrict__ src, u16* __restrict__ dst, int n4) {
  int i = blockIdx.x * 256 + threadIdx.x;
  if (i >= n4) return;
  float4 v = reinterpret_cast<const float4*>(src)[i];
  ushort4 o;
  o.x = f2bf(v.x); o.y = f2bf(v.y); o.z = f2bf(v.z); o.w = f2bf(v.w);
  reinterpret_cast<ushort4*>(dst)[i] = o;
}

// ---------------- mask -> bitmask + row_valid ----------------
__global__ void k_maskpack(const int* __restrict__ mask, u32* __restrict__ mb,
                           u32* __restrict__ rv) {
  int row = blockIdx.x;
  int t = threadIdx.x, w = t >> 6, lane = t & 63;
  const int* mrow = mask + (size_t)row * Sq;
  __shared__ u32 red[4];
  u32 any = 0;
#pragma unroll
  for (int i = 0; i < 4; i++) {
    int chunk = w * 4 + i;
    int k = chunk * 64 + lane;
    u64 bal = __ballot(mrow[k] != 0);
    any |= (u32)(bal | (bal >> 32));
    if (lane == 0) mb[(size_t)row * 32 + chunk * 2]     = (u32)bal;
    if (lane == 1) mb[(size_t)row * 32 + chunk * 2 + 1] = (u32)(bal >> 32);
  }
  if (lane == 0) red[w] = any;
  __syncthreads();
  if (t == 0) rv[row] = (red[0] | red[1] | red[2] | red[3]) ? 1u : 0u;
}

// ---------------- LayerNorm (one block per row) -> bf16 ----------------
__global__ void k_ln(const float* __restrict__ x, const float* __restrict__ g,
                     const float* __restrict__ bb, u16* __restrict__ out) {
  int row = blockIdx.x, t = threadIdx.x;
  float4 v = reinterpret_cast<const float4*>(x + (size_t)row * Dm)[t];
  float s  = v.x + v.y + v.z + v.w;
  float s2 = v.x * v.x + v.y * v.y + v.z * v.z + v.w * v.w;
#pragma unroll
  for (int m = 1; m < 64; m <<= 1) { s += __shfl_xor(s, m); s2 += __shfl_xor(s2, m); }
  __shared__ float rs[4], rs2[4];
  int w = t >> 6;
  if ((t & 63) == 0) { rs[w] = s; rs2[w] = s2; }
  __syncthreads();
  s  = rs[0] + rs[1] + rs[2] + rs[3];
  s2 = rs2[0] + rs2[1] + rs2[2] + rs2[3];
  float mu  = s * (1.0f / Dm);
  float var = s2 * (1.0f / Dm) - mu * mu;
  float r = rsqrtf(var + 1e-5f);
  float4 gv = reinterpret_cast<const float4*>(g)[t];
  float4 bv = reinterpret_cast<const float4*>(bb)[t];
  ushort4 o;
  o.x = f2bf((v.x - mu) * r * gv.x + bv.x);
  o.y = f2bf((v.y - mu) * r * gv.y + bv.y);
  o.z = f2bf((v.z - mu) * r * gv.z + bv.z);
  o.w = f2bf((v.w - mu) * r * gv.w + bv.w);
  reinterpret_cast<ushort4*>(out + (size_t)row * Dm)[t] = o;
}

// ---------------- GEMM 128x128: C[M,N] = A[M,K] * Bw[N,K]^T ----------------
// MODE 0: store bf16
// MODE 2: bf16 out = gelu(acc + bias)
template <int MODE>
__global__ __launch_bounds__(256)
void k_gemm(const u16* __restrict__ A, const u16* __restrict__ Bw,
            int M, int N, int K,
            const float* __restrict__ bias, void* __restrict__ Cout) {
  __shared__ u16 As[128 * 64];
  __shared__ u16 Bs[128 * 64];
  const int t = threadIdx.x;
  const int lane = t & 63, w = t >> 6;
  const int wr = w >> 1, wc = w & 1;
  const int m0 = blockIdx.y * 128, n0 = blockIdx.x * 128;
  const int lr = lane & 15, lk = (lane >> 4) * 8;

  f32x4 acc[4][4] = {};

  for (int kt = 0; kt < K; kt += 64) {
#pragma unroll
    for (int i = 0; i < 4; i++) {
      int cc = i * 256 + t; int row = cc >> 3, c8 = cc & 7;
      gld16(A + (size_t)(m0 + row) * K + kt + c8 * 8, &As[cc * 8]);
    }
#pragma unroll
    for (int i = 0; i < 4; i++) {
      int cc = i * 256 + t; int row = cc >> 3, c8 = cc & 7;
      gld16(Bw + (size_t)(n0 + row) * K + kt + c8 * 8, &Bs[cc * 8]);
    }
    __syncthreads();
#pragma unroll
    for (int kk = 0; kk < 2; kk++) {
      bf16x8 af[4], bfg[4];
#pragma unroll
      for (int m = 0; m < 4; m++)
        af[m] = *reinterpret_cast<const bf16x8*>(&As[(wr * 64 + m * 16 + lr) * 64 + kk * 32 + lk]);
#pragma unroll
      for (int n = 0; n < 4; n++)
        bfg[n] = *reinterpret_cast<const bf16x8*>(&Bs[(wc * 64 + n * 16 + lr) * 64 + kk * 32 + lk]);
#pragma unroll
      for (int m = 0; m < 4; m++)
#pragma unroll
        for (int n = 0; n < 4; n++)
          acc[m][n] = __builtin_amdgcn_mfma_f32_16x16x32_bf16(af[m], bfg[n], acc[m][n], 0, 0, 0);
    }
    __syncthreads();
  }

#pragma unroll
  for (int m = 0; m < 4; m++) {
    const int rowb = m0 + wr * 64 + m * 16 + (lane >> 4) * 4;
#pragma unroll
    for (int n = 0; n < 4; n++) {
      const int col = n0 + wc * 64 + n * 16 + lr;
#pragma unroll
      for (int r = 0; r < 4; r++) {
        const int row = rowb + r;
        float v = acc[m][n][r];
        size_t idx = (size_t)row * N + col;
        if constexpr (MODE == 0) {
          ((u16*)Cout)[idx] = f2bf(v);
        } else {
          float xx = v + bias[col];
          float gl = 0.5f * xx * (1.0f + erff(xx * 0.70710678118f));
          ((u16*)Cout)[idx] = f2bf(gl);
        }
      }
    }
  }
}

// ---------------- GEMM 128x64 (for N=1024 shapes -> 512 blocks = 2/CU) ----------
// MODE 1: f32 out = resid + acc
// MODE 3: f32 out = resid + (rv[row] ? acc + bias : 0)
template <int MODE>
__global__ __launch_bounds__(256)
void k_gemm64(const u16* __restrict__ A, const u16* __restrict__ Bw,
              int M, int N, int K,
              const float* __restrict__ resid, const float* __restrict__ bias,
              const u32* __restrict__ rv, float* __restrict__ Cout) {
  __shared__ u16 As[128 * 64];
  __shared__ u16 Bs[64 * 64];
  const int t = threadIdx.x;
  const int lane = t & 63, w = t >> 6;           // wave w owns rows w*32..w*32+31
  const int m0 = blockIdx.y * 128, n0 = blockIdx.x * 64;
  const int lr = lane & 15, lk = (lane >> 4) * 8;

  f32x4 acc[2][4] = {};

  for (int kt = 0; kt < K; kt += 64) {
#pragma unroll
    for (int i = 0; i < 4; i++) {
      int cc = i * 256 + t; int row = cc >> 3, c8 = cc & 7;
      gld16(A + (size_t)(m0 + row) * K + kt + c8 * 8, &As[cc * 8]);
    }
#pragma unroll
    for (int i = 0; i < 2; i++) {
      int cc = i * 256 + t; int row = cc >> 3, c8 = cc & 7;
      gld16(Bw + (size_t)(n0 + row) * K + kt + c8 * 8, &Bs[cc * 8]);
    }
    __syncthreads();
#pragma unroll
    for (int kk = 0; kk < 2; kk++) {
      bf16x8 af[2], bfg[4];
#pragma unroll
      for (int m = 0; m < 2; m++)
        af[m] = *reinterpret_cast<const bf16x8*>(&As[(w * 32 + m * 16 + lr) * 64 + kk * 32 + lk]);
#pragma unroll
      for (int n = 0; n < 4; n++)
        bfg[n] = *reinterpret_cast<const bf16x8*>(&Bs[(n * 16 + lr) * 64 + kk * 32 + lk]);
#pragma unroll
      for (int m = 0; m < 2; m++)
#pragma unroll
        for (int n = 0; n < 4; n++)
          acc[m][n] = __builtin_amdgcn_mfma_f32_16x16x32_bf16(af[m], bfg[n], acc[m][n], 0, 0, 0);
    }
    __syncthreads();
  }

#pragma unroll
  for (int m = 0; m < 2; m++) {
    const int rowb = m0 + w * 32 + m * 16 + (lane >> 4) * 4;
#pragma unroll
    for (int n = 0; n < 4; n++) {
      const int col = n0 + n * 16 + lr;
#pragma unroll
      for (int r = 0; r < 4; r++) {
        const int row = rowb + r;
        float v = acc[m][n][r];
        size_t idx = (size_t)row * N + col;
        if constexpr (MODE == 1) {
          Cout[idx] = resid[idx] + v;
        } else {
          float y = rv[row] ? (v + bias[col]) : 0.0f;
          Cout[idx] = resid[idx] + y;
        }
      }
    }
  }
}

// ---------------- Flash attention ----------------
// grid (S/64, B*H); 256 thr = 4 waves, each wave owns 16 q rows.
// Q/K/V live in the fused qkv buffer: row stride QS, col offsets 0/1024/2048.
__global__ __launch_bounds__(256)
void k_attn(const u16* __restrict__ qkv, const u32* __restrict__ mb,
            u16* __restrict__ ctxb) {
  __shared__ u16 Qs[64 * 64];
  __shared__ u16 Ks[64 * 64];
  __shared__ u16 Vts[64 * 64];
  __shared__ u16 Ps[4 * 16 * 64];
  const int t = threadIdx.x, lane = t & 63, w = t >> 6;
  const int q0 = blockIdx.x * 64;
  const int bh = blockIdx.y, b = bh >> 4, h = bh & 15;
  const int lr = lane & 15, lkq = (lane >> 4) * 8;
  const size_t baseq = (size_t)(b * Sq) * QS + h * 64;

  // stage Q (swizzled: elem col ^= (row&7)<<3, preserves 8-elem chunks)
  {
    int r = t >> 2, c0 = (t & 3) * 16;
    const u16* gp = qkv + baseq + (size_t)(q0 + r) * QS + c0;
    uint4 v0 = *reinterpret_cast<const uint4*>(gp);
    uint4 v1 = *reinterpret_cast<const uint4*>(gp + 8);
    int sw = (r & 7) << 3;
    *reinterpret_cast<uint4*>(&Qs[r * 64 + (c0 ^ sw)]) = v0;
    *reinterpret_cast<uint4*>(&Qs[r * 64 + ((c0 + 8) ^ sw)]) = v1;
  }
  __syncthreads();

  bf16x8 qf[2];
  const int qrow = w * 16 + lr;
#pragma unroll
  for (int kk = 0; kk < 2; kk++)
    qf[kk] = *reinterpret_cast<const bf16x8*>(&Qs[qrow * 64 + ((kk * 32 + lkq) ^ ((qrow & 7) << 3))]);

  float m_i[4] = {-1e30f, -1e30f, -1e30f, -1e30f};
  float l_i[4] = {0.f, 0.f, 0.f, 0.f};
  f32x4 accO[4] = {};
  const int rq0 = (lane >> 4) * 4;

  for (int kt = 0; kt < Sq / 64; kt++) {
    __syncthreads();
    {
      int r = t >> 2, c0 = (t & 3) * 16;
      const u16* gp = qkv + baseq + 1024 + (size_t)(kt * 64 + r) * QS + c0;
      uint4 v0 = *reinterpret_cast<const uint4*>(gp);
      uint4 v1 = *reinterpret_cast<const uint4*>(gp + 8);
      int sw = (r & 7) << 3;
      *reinterpret_cast<uint4*>(&Ks[r * 64 + (c0 ^ sw)]) = v0;
      *reinterpret_cast<uint4*>(&Ks[r * 64 + ((c0 + 8) ^ sw)]) = v1;
      // V transposed into LDS: Vts[d][k]
      const u16* gv = qkv + baseq + 2048 + (size_t)(kt * 64 + r) * QS + c0;
      u16 tmp[16];
      *reinterpret_cast<uint4*>(&tmp[0]) = *reinterpret_cast<const uint4*>(gv);
      *reinterpret_cast<uint4*>(&tmp[8]) = *reinterpret_cast<const uint4*>(gv + 8);
#pragma unroll
      for (int j = 0; j < 16; j++) {
        int d = c0 + j;
        Vts[d * 64 + (r ^ ((d & 7) << 3))] = tmp[j];
      }
    }
    __syncthreads();

    // QK^T
    f32x4 sc[4];
#pragma unroll
    for (int n = 0; n < 4; n++) sc[n] = (f32x4){0.f, 0.f, 0.f, 0.f};
#pragma unroll
    for (int kk = 0; kk < 2; kk++) {
#pragma unroll
      for (int n = 0; n < 4; n++) {
        int krow = n * 16 + lr;
        bf16x8 kf = *reinterpret_cast<const bf16x8*>(
            &Ks[krow * 64 + ((kk * 32 + lkq) ^ ((krow & 7) << 3))]);
        sc[n] = __builtin_amdgcn_mfma_f32_16x16x32_bf16(qf[kk], kf, sc[n], 0, 0, 0);
      }
    }
    // mask words for this lane's 4 rows
    u32 mw[4][2];
#pragma unroll
    for (int r = 0; r < 4; r++) {
      int q = q0 + w * 16 + rq0 + r;
      mw[r][0] = mb[(size_t)(b * Sq + q) * 32 + kt * 2];
      mw[r][1] = mb[(size_t)(b * Sq + q) * 32 + kt * 2 + 1];
    }
    float rmax[4] = {-1e30f, -1e30f, -1e30f, -1e30f};
#pragma unroll
    for (int n = 0; n < 4; n++) {
      int kin = n * 16 + lr;
#pragma unroll
      for (int r = 0; r < 4; r++) {
        float sval = sc[n][r] * 0.125f;
        if (!((mw[r][kin >> 5] >> (kin & 31)) & 1)) sval = -1e9f;
        sc[n][r] = sval;
        rmax[r] = fmaxf(rmax[r], sval);
      }
    }
#pragma unroll
    for (int r = 0; r < 4; r++) {
#pragma unroll
      for (int mm = 1; mm < 16; mm <<= 1) rmax[r] = fmaxf(rmax[r], __shfl_xor(rmax[r], mm));
      float mnew = fmaxf(m_i[r], rmax[r]);
      float scale = __expf(m_i[r] - mnew);
      m_i[r] = mnew;
      l_i[r] *= scale;
#pragma unroll
      for (int n = 0; n < 4; n++) accO[n][r] *= scale;
    }
    float rsum[4] = {0.f, 0.f, 0.f, 0.f};
#pragma unroll
    for (int n = 0; n < 4; n++)
#pragma unroll
      for (int r = 0; r < 4; r++) {
        float p = __expf(sc[n][r] - m_i[r]);
        sc[n][r] = p;
        rsum[r] += p;
      }
#pragma unroll
    for (int r = 0; r < 4; r++) {
#pragma unroll
      for (int mm = 1; mm < 16; mm <<= 1) rsum[r] += __shfl_xor(rsum[r], mm);
      l_i[r] += rsum[r];
    }
    // P -> LDS (per-wave region, swizzled)
#pragma unroll
    for (int n = 0; n < 4; n++)
#pragma unroll
      for (int r = 0; r < 4; r++) {
        int row = rq0 + r;
        Ps[w * 1024 + row * 64 + ((n * 16 + lr) ^ ((row & 7) << 3))] = f2bf(sc[n][r]);
      }
    asm volatile("s_waitcnt lgkmcnt(0)" ::: "memory");
    __builtin_amdgcn_sched_barrier(0);
    // PV
    bf16x8 pf[2];
#pragma unroll
    for (int kk = 0; kk < 2; kk++)
      pf[kk] = *reinterpret_cast<const bf16x8*>(
          &Ps[w * 1024 + lr * 64 + ((kk * 32 + lkq) ^ ((lr & 7) << 3))]);
#pragma unroll
    for (int kk = 0; kk < 2; kk++) {
#pragma unroll
      for (int n = 0; n < 4; n++) {
        int d = n * 16 + lr;
        bf16x8 vf = *reinterpret_cast<const bf16x8*>(
            &Vts[d * 64 + ((kk * 32 + lkq) ^ ((d & 7) << 3))]);
        accO[n] = __builtin_amdgcn_mfma_f32_16x16x32_bf16(pf[kk], vf, accO[n], 0, 0, 0);
      }
    }
  }

#pragma unroll
  for (int r = 0; r < 4; r++) {
    float recip = (m_i[r] <= -0.9e9f || l_i[r] == 0.f) ? 0.f : 1.f / l_i[r];
    int grow = q0 + w * 16 + rq0 + r;
#pragma unroll
    for (int n = 0; n < 4; n++)
      ctxb[(size_t)(b * Sq + grow) * Dm + h * 64 + n * 16 + lr] = f2bf(accO[n][r] * recip);
  }
}

// ---------------- launch ----------------
extern "C" void kernel_launch(void* const* d_in, const int* in_sizes, int n_in,
                              void* d_out, int out_size, void* d_ws, size_t ws_size,
                              hipStream_t stream) {
  const float* x     = (const float*)d_in[0];
  const float* Wq    = (const float*)d_in[1];
  const float* Wk    = (const float*)d_in[2];
  const float* Wv    = (const float*)d_in[3];
  const float* Wo    = (const float*)d_in[4];
  const float* w1    = (const float*)d_in[5];
  const float* b1    = (const float*)d_in[6];
  const float* w2    = (const float*)d_in[7];
  const float* b2    = (const float*)d_in[8];
  const float* ln1g  = (const float*)d_in[9];
  const float* ln1b  = (const float*)d_in[10];
  const float* ln2g  = (const float*)d_in[11];
  const float* ln2b  = (const float*)d_in[12];
  const int*   mask  = (const int*)d_in[13];
  float* out = (float*)d_out;

  char* ws = (char*)d_ws;
  const size_t MB = 1024 * 1024;
  // [0, 6.3M)   wqkv_b (3072 x 1024 bf16)
  // [6.5, 8.5)  wo_b   [8.5, 17) w1_b   [17, 25.5) w2_b
  // [25.5, 34)  h_b (ln out, reused)
  // [34, ~34.6) mbits + rv
  // [35, 60.2)  qkv (4096 x 3072 bf16); dead after attn
  // [60.5, 69)  ctxb; dead after Wo gemm
  // [35, 68.5)  a1b (4096 x 4096 bf16) reuses qkv+ctxb after both dead
  u16* wqkv_b = (u16*)(ws + 0 * MB);
  u16* wo_b   = (u16*)(ws + 13 * MB / 2);
  u16* w1_b   = (u16*)(ws + 17 * MB / 2);
  u16* w2_b   = (u16*)(ws + 17 * MB);
  u16* h_b    = (u16*)(ws + 51 * MB / 2);
  u32* mbits  = (u32*)(ws + 34 * MB);
  u32* rv     = (u32*)(ws + 34 * MB + 600 * 1024);
  u16* qkv    = (u16*)(ws + 35 * MB);
  u16* ctxb   = (u16*)(ws + 121 * MB / 2);
  u16* a1b    = (u16*)(ws + 35 * MB);
  float* x1   = out;   // attention-sublayer result lives in d_out (in-place resid for w2)

  k_cvt<<<1024, 256, 0, stream>>>(Wq, wqkv_b,               262144);
  k_cvt<<<1024, 256, 0, stream>>>(Wk, wqkv_b + 1024 * 1024, 262144);
  k_cvt<<<1024, 256, 0, stream>>>(Wv, wqkv_b + 2048 * 1024, 262144);
  k_cvt<<<1024, 256, 0, stream>>>(Wo, wo_b, 262144);
  k_cvt<<<4096, 256, 0, stream>>>(w1, w1_b, 1048576);
  k_cvt<<<4096, 256, 0, stream>>>(w2, w2_b, 1048576);
  k_maskpack<<<4096, 256, 0, stream>>>(mask, mbits, rv);
  k_ln<<<4096, 256, 0, stream>>>(x, ln1g, ln1b, h_b);

  // fused QKV: M=4096, N=3072, K=1024 -> 24x32 = 768 blocks (3/CU)
  dim3 gqkv(QS / 128, Mtok / 128);
  k_gemm<0><<<gqkv, 256, 0, stream>>>(h_b, wqkv_b, Mtok, QS, Dm, nullptr, qkv);

  dim3 ga(Sq / 64, Bz * Hn);
  k_attn<<<ga, 256, 0, stream>>>(qkv, mbits, ctxb);

  // Wo: M=4096, N=1024, K=1024 -> BN=64 tile: 16x32 = 512 blocks (2/CU)
  dim3 gwo(Dm / 64, Mtok / 128);
  k_gemm64<1><<<gwo, 256, 0, stream>>>(ctxb, wo_b, Mtok, Dm, Dm, x, nullptr, nullptr, x1);

  k_ln<<<4096, 256, 0, stream>>>(x1, ln2g, ln2b, h_b);

  // w1: M=4096, N=4096, K=1024 -> 32x32 = 1024 blocks (4/CU)
  dim3 g2(Ff / 128, Mtok / 128);
  k_gemm<2><<<g2, 256, 0, stream>>>(h_b, w1_b, Mtok, Ff, Dm, b1, a1b);

  // w2: M=4096, N=1024, K=4096 -> BN=64 tile: 16x32 = 512 blocks (2/CU)
  dim3 gw2(Dm / 64, Mtok / 128);
  k_gemm64<3><<<gw2, 256, 0, stream>>>(a1b, w2_b, Mtok, Dm, Ff, x1, b2, rv, out);
}

// Round 7
// 454.119 us; speedup vs baseline: 1.1541x; 1.0050x over previous
//
#include <hip/hip_runtime.h>

typedef unsigned short u16;
typedef unsigned int   u32;
typedef unsigned long long u64;

typedef __bf16 bf16_t;
typedef bf16_t bf16x8 __attribute__((ext_vector_type(8)));
typedef float  f32x4  __attribute__((ext_vector_type(4)));

static constexpr int Bz = 4, Sq = 1024, Dm = 1024, Hn = 16, Ff = 4096, Mtok = 4096;
static constexpr int QS = 3072;   // fused qkv row stride

static __device__ __forceinline__ u16 f2bf(float f) {
  u32 u = __builtin_bit_cast(u32, f);
  u32 r = u + 0x7fff + ((u >> 16) & 1);
  return (u16)(r >> 16);
}

static __device__ __forceinline__ void gld16(const u16* g, u16* l) {
  __builtin_amdgcn_global_load_lds((const __attribute__((address_space(1))) u32*)g,
                                   (__attribute__((address_space(3))) u32*)l, 16, 0, 0);
}

// ---------------- fp32 -> bf16 cast ----------------
__global__ void k_cvt(const float* __restrict__ src, u16* __restrict__ dst, int n4) {
  int i = blockIdx.x * 256 + threadIdx.x;
  if (i >= n4) return;
  float4 v = reinterpret_cast<const float4*>(src)[i];
  ushort4 o;
  o.x = f2bf(v.x); o.y = f2bf(v.y); o.z = f2bf(v.z); o.w = f2bf(v.w);
  reinterpret_cast<ushort4*>(dst)[i] = o;
}

// ---------------- mask -> bitmask + row_valid ----------------
__global__ void k_maskpack(const int* __restrict__ mask, u32* __restrict__ mb,
                           u32* __restrict__ rv) {
  int row = blockIdx.x;
  int t = threadIdx.x, w = t >> 6, lane = t & 63;
  const int* mrow = mask + (size_t)row * Sq;
  __shared__ u32 red[4];
  u32 any = 0;
#pragma unroll
  for (int i = 0; i < 4; i++) {
    int chunk = w * 4 + i;
    int k = chunk * 64 + lane;
    u64 bal = __ballot(mrow[k] != 0);
    any |= (u32)(bal | (bal >> 32));
    if (lane == 0) mb[(size_t)row * 32 + chunk * 2]     = (u32)bal;
    if (lane == 1) mb[(size_t)row * 32 + chunk * 2 + 1] = (u32)(bal >> 32);
  }
  if (lane == 0) red[w] = any;
  __syncthreads();
  if (t == 0) rv[row] = (red[0] | red[1] | red[2] | red[3]) ? 1u : 0u;
}

// ---------------- LayerNorm (one block per row) -> bf16 ----------------
__global__ void k_ln(const float* __restrict__ x, const float* __restrict__ g,
                     const float* __restrict__ bb, u16* __restrict__ out) {
  int row = blockIdx.x, t = threadIdx.x;
  float4 v = reinterpret_cast<const float4*>(x + (size_t)row * Dm)[t];
  float s  = v.x + v.y + v.z + v.w;
  float s2 = v.x * v.x + v.y * v.y + v.z * v.z + v.w * v.w;
#pragma unroll
  for (int m = 1; m < 64; m <<= 1) { s += __shfl_xor(s, m); s2 += __shfl_xor(s2, m); }
  __shared__ float rs[4], rs2[4];
  int w = t >> 6;
  if ((t & 63) == 0) { rs[w] = s; rs2[w] = s2; }
  __syncthreads();
  s  = rs[0] + rs[1] + rs[2] + rs[3];
  s2 = rs2[0] + rs2[1] + rs2[2] + rs2[3];
  float mu  = s * (1.0f / Dm);
  float var = s2 * (1.0f / Dm) - mu * mu;
  float r = rsqrtf(var + 1e-5f);
  float4 gv = reinterpret_cast<const float4*>(g)[t];
  float4 bv = reinterpret_cast<const float4*>(bb)[t];
  ushort4 o;
  o.x = f2bf((v.x - mu) * r * gv.x + bv.x);
  o.y = f2bf((v.y - mu) * r * gv.y + bv.y);
  o.z = f2bf((v.z - mu) * r * gv.z + bv.z);
  o.w = f2bf((v.w - mu) * r * gv.w + bv.w);
  reinterpret_cast<ushort4*>(out + (size_t)row * Dm)[t] = o;
}

// ---------------- GEMM 128x128: C[M,N] = A[M,K] * Bw[N,K]^T ----------------
// MODE 0: store bf16; cols >= 2048 go TRANSPOSED to vTout[bh][d][tok] (V for attn)
// MODE 2: bf16 out = gelu(acc + bias)
template <int MODE>
__global__ __launch_bounds__(256)
void k_gemm(const u16* __restrict__ A, const u16* __restrict__ Bw,
            int M, int N, int K,
            const float* __restrict__ bias, void* __restrict__ Cout,
            u16* __restrict__ vTout) {
  __shared__ u16 As[128 * 64];
  __shared__ u16 Bs[128 * 64];
  const int t = threadIdx.x;
  const int lane = t & 63, w = t >> 6;
  const int wr = w >> 1, wc = w & 1;
  const int m0 = blockIdx.y * 128, n0 = blockIdx.x * 128;
  const int lr = lane & 15, lk = (lane >> 4) * 8;

  f32x4 acc[4][4] = {};

  for (int kt = 0; kt < K; kt += 64) {
#pragma unroll
    for (int i = 0; i < 4; i++) {
      int cc = i * 256 + t; int row = cc >> 3, c8 = cc & 7;
      gld16(A + (size_t)(m0 + row) * K + kt + c8 * 8, &As[cc * 8]);
    }
#pragma unroll
    for (int i = 0; i < 4; i++) {
      int cc = i * 256 + t; int row = cc >> 3, c8 = cc & 7;
      gld16(Bw + (size_t)(n0 + row) * K + kt + c8 * 8, &Bs[cc * 8]);
    }
    __syncthreads();
#pragma unroll
    for (int kk = 0; kk < 2; kk++) {
      bf16x8 af[4], bfg[4];
#pragma unroll
      for (int m = 0; m < 4; m++)
        af[m] = *reinterpret_cast<const bf16x8*>(&As[(wr * 64 + m * 16 + lr) * 64 + kk * 32 + lk]);
#pragma unroll
      for (int n = 0; n < 4; n++)
        bfg[n] = *reinterpret_cast<const bf16x8*>(&Bs[(wc * 64 + n * 16 + lr) * 64 + kk * 32 + lk]);
#pragma unroll
      for (int m = 0; m < 4; m++)
#pragma unroll
        for (int n = 0; n < 4; n++)
          acc[m][n] = __builtin_amdgcn_mfma_f32_16x16x32_bf16(af[m], bfg[n], acc[m][n], 0, 0, 0);
    }
    __syncthreads();
  }

  if constexpr (MODE == 0) {
    if (n0 >= 2048) {
      // V part of fused QKV: write transposed vT[(b*16+h)*64 + d][tok], 4 tok packed.
#pragma unroll
      for (int m = 0; m < 4; m++) {
        const int rowb = m0 + wr * 64 + m * 16 + (lane >> 4) * 4;
        const int bb = rowb >> 10, tok = rowb & 1023;
#pragma unroll
        for (int n = 0; n < 4; n++) {
          const int dfull = n0 + wc * 64 + n * 16 + lr - 2048;
          ushort4 o4;
          o4.x = f2bf(acc[m][n][0]); o4.y = f2bf(acc[m][n][1]);
          o4.z = f2bf(acc[m][n][2]); o4.w = f2bf(acc[m][n][3]);
          size_t idx = ((size_t)((bb * 16 + (dfull >> 6)) * 64 + (dfull & 63))) * 1024 + tok;
          *reinterpret_cast<ushort4*>(vTout + idx) = o4;
        }
      }
      return;
    }
  }

#pragma unroll
  for (int m = 0; m < 4; m++) {
    const int rowb = m0 + wr * 64 + m * 16 + (lane >> 4) * 4;
#pragma unroll
    for (int n = 0; n < 4; n++) {
      const int col = n0 + wc * 64 + n * 16 + lr;
#pragma unroll
      for (int r = 0; r < 4; r++) {
        const int row = rowb + r;
        float v = acc[m][n][r];
        size_t idx = (size_t)row * N + col;
        if constexpr (MODE == 0) {
          ((u16*)Cout)[idx] = f2bf(v);
        } else {
          float xx = v + bias[col];
          float gl = 0.5f * xx * (1.0f + erff(xx * 0.70710678118f));
          ((u16*)Cout)[idx] = f2bf(gl);
        }
      }
    }
  }
}

// ---------------- GEMM 128x64 (N=1024 shapes -> 512 blocks = 2/CU) ----------
// MODE 1: f32 out = resid + acc
// MODE 3: f32 out = resid + (rv[row] ? acc + bias : 0)
template <int MODE>
__global__ __launch_bounds__(256)
void k_gemm64(const u16* __restrict__ A, const u16* __restrict__ Bw,
              int M, int N, int K,
              const float* __restrict__ resid, const float* __restrict__ bias,
              const u32* __restrict__ rv, float* __restrict__ Cout) {
  __shared__ u16 As[128 * 64];
  __shared__ u16 Bs[64 * 64];
  const int t = threadIdx.x;
  const int lane = t & 63, w = t >> 6;           // wave w owns rows w*32..w*32+31
  const int m0 = blockIdx.y * 128, n0 = blockIdx.x * 64;
  const int lr = lane & 15, lk = (lane >> 4) * 8;

  f32x4 acc[2][4] = {};

  for (int kt = 0; kt < K; kt += 64) {
#pragma unroll
    for (int i = 0; i < 4; i++) {
      int cc = i * 256 + t; int row = cc >> 3, c8 = cc & 7;
      gld16(A + (size_t)(m0 + row) * K + kt + c8 * 8, &As[cc * 8]);
    }
#pragma unroll
    for (int i = 0; i < 2; i++) {
      int cc = i * 256 + t; int row = cc >> 3, c8 = cc & 7;
      gld16(Bw + (size_t)(n0 + row) * K + kt + c8 * 8, &Bs[cc * 8]);
    }
    __syncthreads();
#pragma unroll
    for (int kk = 0; kk < 2; kk++) {
      bf16x8 af[2], bfg[4];
#pragma unroll
      for (int m = 0; m < 2; m++)
        af[m] = *reinterpret_cast<const bf16x8*>(&As[(w * 32 + m * 16 + lr) * 64 + kk * 32 + lk]);
#pragma unroll
      for (int n = 0; n < 4; n++)
        bfg[n] = *reinterpret_cast<const bf16x8*>(&Bs[(n * 16 + lr) * 64 + kk * 32 + lk]);
#pragma unroll
      for (int m = 0; m < 2; m++)
#pragma unroll
        for (int n = 0; n < 4; n++)
          acc[m][n] = __builtin_amdgcn_mfma_f32_16x16x32_bf16(af[m], bfg[n], acc[m][n], 0, 0, 0);
    }
    __syncthreads();
  }

#pragma unroll
  for (int m = 0; m < 2; m++) {
    const int rowb = m0 + w * 32 + m * 16 + (lane >> 4) * 4;
#pragma unroll
    for (int n = 0; n < 4; n++) {
      const int col = n0 + n * 16 + lr;
#pragma unroll
      for (int r = 0; r < 4; r++) {
        const int row = rowb + r;
        float v = acc[m][n][r];
        size_t idx = (size_t)row * N + col;
        if constexpr (MODE == 1) {
          Cout[idx] = resid[idx] + v;
        } else {
          float y = rv[row] ? (v + bias[col]) : 0.0f;
          Cout[idx] = resid[idx] + y;
        }
      }
    }
  }
}

// ---------------- Flash attention v2 ----------------
// grid (S/64, B*H); 4 waves x 16 q-rows. K and V^T staged via global_load_lds
// with PRE-SWIZZLED global source (linear LDS dest, XOR-swz read), double-buffered.
// Qs is reused as K-buffer 1 after Q moves to registers. LDS = 5*8KB = 40960 B
// -> exactly 4 blocks/CU.
__global__ __launch_bounds__(256)
void k_attn(const u16* __restrict__ qkv, const u16* __restrict__ vT,
            const u32* __restrict__ mb, u16* __restrict__ ctxb) {
  __shared__ u16 Qs[4096];    // doubles as K buf 1
  __shared__ u16 Ks0[4096];
  __shared__ u16 Vt0[4096];
  __shared__ u16 Vt1[4096];
  __shared__ u16 Ps[4096];
  const int t = threadIdx.x, lane = t & 63, w = t >> 6;
  const int q0 = blockIdx.x * 64;
  const int bh = blockIdx.y, b = bh >> 4, h = bh & 15;
  const int lr = lane & 15, lkq = (lane >> 4) * 8;

  const size_t qbase = (size_t)(b * Sq + q0) * QS + h * 64;
  const size_t kbase = (size_t)(b * Sq) * QS + 1024 + h * 64;
  const size_t vbase = (size_t)bh * 64 * 1024;

  auto stageK = [&](u16* dst, int kt) {
#pragma unroll
    for (int j = 0; j < 2; j++) {
      int cc = j * 256 + t, r = cc >> 3, ch = cc & 7;
      gld16(qkv + kbase + (size_t)(kt * 64 + r) * QS + ((ch ^ (r & 7)) * 8), dst + cc * 8);
    }
  };
  auto stageV = [&](u16* dst, int kt) {
#pragma unroll
    for (int j = 0; j < 2; j++) {
      int cc = j * 256 + t, d = cc >> 3, ch = cc & 7;
      gld16(vT + vbase + (size_t)d * 1024 + kt * 64 + ((ch ^ (d & 7)) * 8), dst + cc * 8);
    }
  };

  // prologue: stage Q + tile 0
  {
#pragma unroll
    for (int j = 0; j < 2; j++) {
      int cc = j * 256 + t, r = cc >> 3, ch = cc & 7;
      gld16(qkv + qbase + (size_t)r * QS + ((ch ^ (r & 7)) * 8), &Qs[cc * 8]);
    }
  }
  stageK(Ks0, 0);
  stageV(Vt0, 0);
  __syncthreads();

  bf16x8 qf[2];
  const int qrow = w * 16 + lr;
#pragma unroll
  for (int kk = 0; kk < 2; kk++)
    qf[kk] = *reinterpret_cast<const bf16x8*>(&Qs[qrow * 64 + ((kk * 32 + lkq) ^ ((qrow & 7) << 3))]);
  __syncthreads();   // Qs now free for reuse as K buf 1

  float m_i[4] = {-1e30f, -1e30f, -1e30f, -1e30f};
  float l_i[4] = {0.f, 0.f, 0.f, 0.f};
  f32x4 accO[4] = {};
  const int rq0 = (lane >> 4) * 4;

  for (int kt = 0; kt < Sq / 64; kt++) {
    u16* kb = (kt & 1) ? Qs : Ks0;
    u16* vb = (kt & 1) ? Vt1 : Vt0;
    if (kt + 1 < Sq / 64) {          // prefetch next tile (in flight across compute)
      stageK((kt & 1) ? Ks0 : Qs, kt + 1);
      stageV((kt & 1) ? Vt0 : Vt1, kt + 1);
    }
    // mask words for this lane's 4 rows (issue early, overlap latency)
    u32 mw0[4], mw1[4];
#pragma unroll
    for (int r = 0; r < 4; r++) {
      int q = q0 + w * 16 + rq0 + r;
      mw0[r] = mb[(size_t)(b * Sq + q) * 32 + kt * 2];
      mw1[r] = mb[(size_t)(b * Sq + q) * 32 + kt * 2 + 1];
    }

    // QK^T
    f32x4 sc[4];
#pragma unroll
    for (int n = 0; n < 4; n++) sc[n] = (f32x4){0.f, 0.f, 0.f, 0.f};
#pragma unroll
    for (int kk = 0; kk < 2; kk++) {
#pragma unroll
      for (int n = 0; n < 4; n++) {
        int krow = n * 16 + lr;
        bf16x8 kf = *reinterpret_cast<const bf16x8*>(
            &kb[krow * 64 + ((kk * 32 + lkq) ^ ((krow & 7) << 3))]);
        sc[n] = __builtin_amdgcn_mfma_f32_16x16x32_bf16(qf[kk], kf, sc[n], 0, 0, 0);
      }
    }

    // scale + mask (fast path when both words all-ones) + row max
    float rmax[4] = {-1e30f, -1e30f, -1e30f, -1e30f};
#pragma unroll
    for (int r = 0; r < 4; r++) {
      if ((mw0[r] & mw1[r]) == 0xffffffffu) {
#pragma unroll
        for (int n = 0; n < 4; n++) {
          float sval = sc[n][r] * 0.125f;
          sc[n][r] = sval;
          rmax[r] = fmaxf(rmax[r], sval);
        }
      } else {
#pragma unroll
        for (int n = 0; n < 4; n++) {
          int kin = n * 16 + lr;
          float sval = sc[n][r] * 0.125f;
          u32 word = (kin & 32) ? mw1[r] : mw0[r];
          if (!((word >> (kin & 31)) & 1)) sval = -1e9f;
          sc[n][r] = sval;
          rmax[r] = fmaxf(rmax[r], sval);
        }
      }
    }
    // 16-lane-group reduce + defer-max (skip rescale when growth <= 8)
#pragma unroll
    for (int r = 0; r < 4; r++) {
#pragma unroll
      for (int mm = 1; mm < 16; mm <<= 1) rmax[r] = fmaxf(rmax[r], __shfl_xor(rmax[r], mm));
      float mnew = fmaxf(m_i[r], rmax[r]);
      if (mnew - m_i[r] > 8.0f) {
        float scale = __expf(m_i[r] - mnew);
        m_i[r] = mnew;
        l_i[r] *= scale;
#pragma unroll
        for (int n = 0; n < 4; n++) accO[n][r] *= scale;
      }
    }
    float rsum[4] = {0.f, 0.f, 0.f, 0.f};
#pragma unroll
    for (int n = 0; n < 4; n++)
#pragma unroll
      for (int r = 0; r < 4; r++) {
        float p = __expf(sc[n][r] - m_i[r]);
        sc[n][r] = p;
        rsum[r] += p;
      }
#pragma unroll
    for (int r = 0; r < 4; r++) {
#pragma unroll
      for (int mm = 1; mm < 16; mm <<= 1) rsum[r] += __shfl_xor(rsum[r], mm);
      l_i[r] += rsum[r];
    }
    // P -> LDS (per-wave private region, swizzled)
#pragma unroll
    for (int n = 0; n < 4; n++)
#pragma unroll
      for (int r = 0; r < 4; r++) {
        int row = rq0 + r;
        Ps[w * 1024 + row * 64 + ((n * 16 + lr) ^ ((row & 7) << 3))] = f2bf(sc[n][r]);
      }
    asm volatile("s_waitcnt lgkmcnt(0)" ::: "memory");
    __builtin_amdgcn_sched_barrier(0);
    // PV
    bf16x8 pf[2];
#pragma unroll
    for (int kk = 0; kk < 2; kk++)
      pf[kk] = *reinterpret_cast<const bf16x8*>(
          &Ps[w * 1024 + lr * 64 + ((kk * 32 + lkq) ^ ((lr & 7) << 3))]);
#pragma unroll
    for (int kk = 0; kk < 2; kk++) {
#pragma unroll
      for (int n = 0; n < 4; n++) {
        int d = n * 16 + lr;
        bf16x8 vf = *reinterpret_cast<const bf16x8*>(
            &vb[d * 64 + ((kk * 32 + lkq) ^ ((d & 7) << 3))]);
        accO[n] = __builtin_amdgcn_mfma_f32_16x16x32_bf16(pf[kk], vf, accO[n], 0, 0, 0);
      }
    }
    __syncthreads();   // drains vmcnt too: next tile's staged data ready
  }

#pragma unroll
  for (int r = 0; r < 4; r++) {
    float recip = (m_i[r] <= -0.9e9f || l_i[r] == 0.f) ? 0.f : 1.f / l_i[r];
    int grow = q0 + w * 16 + rq0 + r;
#pragma unroll
    for (int n = 0; n < 4; n++)
      ctxb[(size_t)(b * Sq + grow) * Dm + h * 64 + n * 16 + lr] = f2bf(accO[n][r] * recip);
  }
}

// ---------------- launch ----------------
extern "C" void kernel_launch(void* const* d_in, const int* in_sizes, int n_in,
                              void* d_out, int out_size, void* d_ws, size_t ws_size,
                              hipStream_t stream) {
  const float* x     = (const float*)d_in[0];
  const float* Wq    = (const float*)d_in[1];
  const float* Wk    = (const float*)d_in[2];
  const float* Wv    = (const float*)d_in[3];
  const float* Wo    = (const float*)d_in[4];
  const float* w1    = (const float*)d_in[5];
  const float* b1    = (const float*)d_in[6];
  const float* w2    = (const float*)d_in[7];
  const float* b2    = (const float*)d_in[8];
  const float* ln1g  = (const float*)d_in[9];
  const float* ln1b  = (const float*)d_in[10];
  const float* ln2g  = (const float*)d_in[11];
  const float* ln2b  = (const float*)d_in[12];
  const int*   mask  = (const int*)d_in[13];
  float* out = (float*)d_out;

  char* ws = (char*)d_ws;
  const size_t MB = 1024 * 1024;
  // [0, 6)     wqkv_b (3072 x 1024 bf16)
  // [6.5, 8.5) wo_b   [8.5, 17) w1_b   [17, 25.5) w2_b
  // [25.5, 34) h_b    [34, ~34.6) mbits + rv
  // [35, 60.2) qkv (Q,K valid; V-cols unused)   — dead after attn
  // [60.5, 69) ctxb                              — dead after Wo gemm
  // [69, 77)   vT (64bh x 64d x 1024tok bf16)    — dead after attn
  // [35, 68.5) a1b reuses qkv+ctxb after both dead
  u16* wqkv_b = (u16*)(ws + 0 * MB);
  u16* wo_b   = (u16*)(ws + 13 * MB / 2);
  u16* w1_b   = (u16*)(ws + 17 * MB / 2);
  u16* w2_b   = (u16*)(ws + 17 * MB);
  u16* h_b    = (u16*)(ws + 51 * MB / 2);
  u32* mbits  = (u32*)(ws + 34 * MB);
  u32* rv     = (u32*)(ws + 34 * MB + 600 * 1024);
  u16* qkv    = (u16*)(ws + 35 * MB);
  u16* ctxb   = (u16*)(ws + 121 * MB / 2);
  u16* vTb    = (u16*)(ws + 69 * MB);
  u16* a1b    = (u16*)(ws + 35 * MB);
  float* x1   = out;   // attention-sublayer result lives in d_out (in-place resid for w2)

  k_cvt<<<1024, 256, 0, stream>>>(Wq, wqkv_b,               262144);
  k_cvt<<<1024, 256, 0, stream>>>(Wk, wqkv_b + 1024 * 1024, 262144);
  k_cvt<<<1024, 256, 0, stream>>>(Wv, wqkv_b + 2048 * 1024, 262144);
  k_cvt<<<1024, 256, 0, stream>>>(Wo, wo_b, 262144);
  k_cvt<<<4096, 256, 0, stream>>>(w1, w1_b, 1048576);
  k_cvt<<<4096, 256, 0, stream>>>(w2, w2_b, 1048576);
  k_maskpack<<<4096, 256, 0, stream>>>(mask, mbits, rv);
  k_ln<<<4096, 256, 0, stream>>>(x, ln1g, ln1b, h_b);

  // fused QKV: M=4096, N=3072, K=1024 -> 768 blocks (3/CU); V written transposed
  dim3 gqkv(QS / 128, Mtok / 128);
  k_gemm<0><<<gqkv, 256, 0, stream>>>(h_b, wqkv_b, Mtok, QS, Dm, nullptr, qkv, vTb);

  dim3 ga(Sq / 64, Bz * Hn);
  k_attn<<<ga, 256, 0, stream>>>(qkv, vTb, mbits, ctxb);

  // Wo: M=4096, N=1024, K=1024 -> BN=64: 512 blocks (2/CU)
  dim3 gwo(Dm / 64, Mtok / 128);
  k_gemm64<1><<<gwo, 256, 0, stream>>>(ctxb, wo_b, Mtok, Dm, Dm, x, nullptr, nullptr, x1);

  k_ln<<<4096, 256, 0, stream>>>(x1, ln2g, ln2b, h_b);

  // w1: M=4096, N=4096, K=1024 -> 1024 blocks (4/CU)
  dim3 g2(Ff / 128, Mtok / 128);
  k_gemm<2><<<g2, 256, 0, stream>>>(h_b, w1_b, Mtok, Ff, Dm, b1, a1b, nullptr);

  // w2: M=4096, N=1024, K=4096 -> BN=64: 512 blocks (2/CU)
  dim3 gw2(Dm / 64, Mtok / 128);
  k_gemm64<3><<<gw2, 256, 0, stream>>>(a1b, w2_b, Mtok, Dm, Ff, x1, b2, rv, out);
}